// Round 5
// baseline (827.060 us; speedup 1.0000x reference)
//
#include <hip/hip_runtime.h>

typedef unsigned short u16;
typedef unsigned int u32;
typedef __bf16 bf16x8 __attribute__((ext_vector_type(8)));
typedef float f32x4 __attribute__((ext_vector_type(4)));
typedef const __attribute__((address_space(3))) u16* ldsp;

#define B_ROWS 8192

// ---------- helpers ----------
__device__ __forceinline__ float bf2f(u16 h) {
    union { u32 u; float f; } v; v.u = ((u32)h) << 16; return v.f;
}
__device__ __forceinline__ u16 f2bf(float f) {
    union { float f; u32 u; } v; v.f = f;
    u32 r = v.u + 0x7fffu + ((v.u >> 16) & 1u);   // RNE
    return (u16)(r >> 16);
}
// tanh-approx gelu, overflow-safe (e=inf -> th=1)
__device__ __forceinline__ float gelu_fast(float x) {
    float u = x * (0.7978845608f + 0.0356774081f * x * x);
    float e = __expf(2.f * u);
    float th = 1.f - 2.f / (e + 1.f);
    return 0.5f * x * (1.f + th);
}
__device__ __forceinline__ float sigmoid12(float g) {
    return 1.f / (1.f + __expf(-1.2f * g));
}
__device__ __forceinline__ float wave_reduce_sum(float v) {
    #pragma unroll
    for (int m = 32; m; m >>= 1) v += __shfl_xor(v, m, 64);
    return v;
}
__device__ __forceinline__ void async16(const void* g, void* l) {
    __builtin_amdgcn_global_load_lds((const __attribute__((address_space(1))) u32*)g,
                                     (__attribute__((address_space(3))) u32*)l, 16, 0, 0);
}
// inline-asm LDS read: keeps the compiler from seeing an LDS access that
// aliases the global_load_lds writes (it would insert s_waitcnt vmcnt(0)
// and destroy the counted-vmcnt pipeline).
template<int OFF>
__device__ __forceinline__ bf16x8 dsr(ldsp a) {
    bf16x8 r;
    asm volatile("ds_read_b128 %0, %1 offset:%c2"
                 : "=v"(r) : "v"(a), "i"(OFF) : "memory");
    return r;
}

// ---------- absmean stage 1: deterministic block partials (no atomics) ----------
__global__ void absmean1_kernel(const float* __restrict__ w0, const float* __restrict__ w1,
                                const float* __restrict__ w2, const float* __restrict__ w3,
                                float* __restrict__ partials) {
    const float* w = (blockIdx.y == 0) ? w0 : (blockIdx.y == 1) ? w1 : (blockIdx.y == 2) ? w2 : w3;
    int base = blockIdx.x * 16384;   // vec4 units
    float acc = 0.f;
    for (int j = threadIdx.x; j < 16384; j += 256) {
        float4 v = ((const float4*)w)[base + j];
        acc += fabsf(v.x) + fabsf(v.y) + fabsf(v.z) + fabsf(v.w);
    }
    acc = wave_reduce_sum(acc);
    __shared__ float red[4];
    int lane = threadIdx.x & 63, wv = threadIdx.x >> 6;
    if (lane == 0) red[wv] = acc;
    __syncthreads();
    if (threadIdx.x == 0)
        partials[blockIdx.y * 64 + blockIdx.x] = red[0] + red[1] + red[2] + red[3];
}

// ---------- absmean stage 2: fixed-order combine ----------
__global__ void absmean2_kernel(const float* __restrict__ partials, double* __restrict__ sums) {
    float v = partials[blockIdx.x * 64 + threadIdx.x];
    v = wave_reduce_sum(v);
    if (threadIdx.x == 0) sums[blockIdx.x] = (double)v;
}

// ---------- prep: y<4 ternary-quantize {-1,0,1} bf16; y=4,5 cvt mlp weights ----------
__global__ void prep_kernel(const float* __restrict__ w0, const float* __restrict__ w1,
                            const float* __restrict__ w2, const float* __restrict__ w3,
                            const float* __restrict__ mw1, const float* __restrict__ mw2,
                            u16* __restrict__ wq, u16* __restrict__ mwq,
                            const double* __restrict__ sums) {
    int y = blockIdx.y;
    int i = blockIdx.x * 256 + threadIdx.x;   // vec4 index, grid.x = 4096
    if (y < 4) {
        const float* w = (y == 0) ? w0 : (y == 1) ? w1 : (y == 2) ? w2 : w3;
        float s = (float)(sums[y] * (1.0 / 4194304.0));
        float den = s + 1e-5f;
        float4 v = ((const float4*)w)[i];
        ushort4 o;
        o.x = f2bf(rintf(fminf(fmaxf(v.x / den, -1.f), 1.f)));
        o.y = f2bf(rintf(fminf(fmaxf(v.y / den, -1.f), 1.f)));
        o.z = f2bf(rintf(fminf(fmaxf(v.z / den, -1.f), 1.f)));
        o.w = f2bf(rintf(fminf(fmaxf(v.w / den, -1.f), 1.f)));
        ((ushort4*)(wq + (size_t)y * 4194304))[i] = o;
    } else {
        const float* src = (y == 4) ? mw1 : mw2;
        u16* dst = mwq + (y == 4 ? 0 : 8388608);
        #pragma unroll
        for (int r = 0; r < 2; ++r) {
            int j = i + r * 1048576;
            float4 v = ((const float4*)src)[j];
            ushort4 o = {f2bf(v.x), f2bf(v.y), f2bf(v.z), f2bf(v.w)};
            ((ushort4*)dst)[j] = o;
        }
    }
}

// ---------- concat 5 fp32 inputs -> combined [8192,2048] bf16 ----------
__global__ void concat_kernel(const float* __restrict__ zb, const float* __restrict__ za,
                              const float* __restrict__ ze, const float* __restrict__ zm,
                              const float* __restrict__ zs, u16* __restrict__ out) {
    int row = blockIdx.x, t = threadIdx.x;
    int col = t * 8;
    const float* src; int scol, stride;
    if (col < 512)       { src = zb; scol = col;        stride = 512; }
    else if (col < 768)  { src = za; scol = col - 512;  stride = 256; }
    else if (col < 1024) { src = ze; scol = col - 768;  stride = 256; }
    else if (col < 1536) { src = zm; scol = col - 1024; stride = 512; }
    else                 { src = zs; scol = col - 1536; stride = 512; }
    const float4* s4 = (const float4*)(src + (size_t)row * stride + scol);
    float4 a = s4[0], b = s4[1];
    ushort4 p0 = {f2bf(a.x), f2bf(a.y), f2bf(a.z), f2bf(a.w)};
    ushort4 p1 = {f2bf(b.x), f2bf(b.y), f2bf(b.z), f2bf(b.w)};
    u16* o = out + (size_t)row * 2048 + col;
    *(ushort4*)o = p0;
    *(ushort4*)(o + 4) = p1;
}

// ============ 256x256 GEMM, counted-lgkm interleaved pipeline (v4) ============
// C = scale * (A[M,K(lda)] * W[N,K]^T) + bias
// 512 threads = 8 waves (2M x 4N); per-wave output 128x64; BK=64; LDS 128KiB.
// LDS layout: lds[A=0/B=1][dbuf][half(128 rows)][128x64 bf16], rows are 128B.
// T2 swizzle: 16B chunk c stored at c ^ (row&7), realized as pre-swizzled
//   GLOBAL source + linear global_load_lds dest, same XOR on read bases.
//
// v4 structure (within-wave overlap; DS ops retire IN ORDER -> counted
// lgkmcnt gives per-fragment readiness):
//   tile t (read buf d, stage tile t+1 into buf e=d^1):
//     issue 16 ds_reads (A-h0:2+6, B-h0:4, B-h1:4) + 8 global_load_lds (t+1->e)
//     lgkm 10/8/6/4 -> 4x MFMA(0,0) groups ; lgkm 2/0 -> 2x MFMA(0,1) groups
//     issue 8 ds_reads (A-h1) ; lgkm 6/4/2/0 -> 4x MFMA(1,1) groups
//     MFMA(1,0) x16 (all regs live)
//     s_waitcnt vmcnt(0)   (retires t+1's loads, issued ~1 tile earlier: free)
//     s_barrier            (publishes buf e; closes this tile's reads)
// Hazard ledger: staging targets buf e which NO wave reads during tile t
//   (tile t-1's reads of e all retired before t-1's closing barrier: every
//   read region's waits end at lgkmcnt(0) before that barrier). So there are
//   ZERO intra-tile cross-wave hazards -> one barrier per tile (was 4).
// Accumulation order per output element unchanged (ks0,ks1 ascending per
//   k-tile) -> bit-identical numerics vs r3.
#define STG_A(d, h, kt_) { \
    async16(Ab0 + (size_t)(h) * ha + (size_t)(kt_) * 64, &lds[0][d][h][ci0 * 8]); \
    async16(Ab1 + (size_t)(h) * ha + (size_t)(kt_) * 64, &lds[0][d][h][ci1 * 8]); }
#define STG_B(d, h, kt_) { \
    async16(Wb0 + (size_t)(h) * hw + (size_t)(kt_) * 64, &lds[1][d][h][ci0 * 8]); \
    async16(Wb1 + (size_t)(h) * hw + (size_t)(kt_) * 64, &lds[1][d][h][ci1 * 8]); }
#define AOFF(d, h, fm) (((d) * 2 + (h)) * 16384 + (fm) * 2048)
#define BOFF(d, h, fn) (((d) * 2 + (h)) * 16384 + (fn) * 2048)
#define LDA2(d, h, fm) { \
    af[fm][0] = dsr<AOFF(d,h,fm)>(vA0); af[fm][1] = dsr<AOFF(d,h,fm)>(vA1); }
#define LDB_H(d, qn) { \
    bf[qn][0][0] = dsr<BOFF(d,qn,0)>(vB0); bf[qn][0][1] = dsr<BOFF(d,qn,0)>(vB1); \
    bf[qn][1][0] = dsr<BOFF(d,qn,1)>(vB0); bf[qn][1][1] = dsr<BOFF(d,qn,1)>(vB1); }
#define W_LGKM(n) { \
    asm volatile("s_waitcnt lgkmcnt(" n ")" ::: "memory"); \
    __builtin_amdgcn_sched_barrier(0); }
#define MFMA1(qm, qn, fm, fn, ks) \
    acc[qm][qn][fm][fn] = __builtin_amdgcn_mfma_f32_16x16x32_bf16(af[fm][ks], bf[qn][fn][ks], acc[qm][qn][fm][fn], 0, 0, 0);
#define MFMA4(qm, qn, fm) { \
    MFMA1(qm, qn, fm, 0, 0); MFMA1(qm, qn, fm, 0, 1); \
    MFMA1(qm, qn, fm, 1, 0); MFMA1(qm, qn, fm, 1, 1); }
#define MFMA8(qm, qn, fn) { \
    MFMA1(qm, qn, 0, fn, 0); MFMA1(qm, qn, 0, fn, 1); \
    MFMA1(qm, qn, 1, fn, 0); MFMA1(qm, qn, 1, fn, 1); \
    MFMA1(qm, qn, 2, fn, 0); MFMA1(qm, qn, 2, fn, 1); \
    MFMA1(qm, qn, 3, fn, 0); MFMA1(qm, qn, 3, fn, 1); }
#define MFMA16(qm, qn) { MFMA4(qm, qn, 0); MFMA4(qm, qn, 1); MFMA4(qm, qn, 2); MFMA4(qm, qn, 3); }
#define GROUP(ktv, d, e) { \
    LDA2(d, 0, 0); \
    LDB_H(d, 0); \
    LDA2(d, 0, 1); LDA2(d, 0, 2); LDA2(d, 0, 3); \
    LDB_H(d, 1); \
    if ((ktv) + 1 < NT) { \
        STG_A(e, 0, (ktv) + 1); STG_B(e, 0, (ktv) + 1); \
        STG_B(e, 1, (ktv) + 1); STG_A(e, 1, (ktv) + 1); } \
    W_LGKM("10"); __builtin_amdgcn_s_setprio(1); MFMA4(0, 0, 0); \
    W_LGKM("8");  MFMA4(0, 0, 1); \
    W_LGKM("6");  MFMA4(0, 0, 2); \
    W_LGKM("4");  MFMA4(0, 0, 3); \
    W_LGKM("2");  MFMA8(0, 1, 0); \
    W_LGKM("0");  MFMA8(0, 1, 1); __builtin_amdgcn_s_setprio(0); \
    LDA2(d, 1, 0); LDA2(d, 1, 1); LDA2(d, 1, 2); LDA2(d, 1, 3); \
    W_LGKM("6"); __builtin_amdgcn_s_setprio(1); MFMA4(1, 1, 0); \
    W_LGKM("4"); MFMA4(1, 1, 1); \
    W_LGKM("2"); MFMA4(1, 1, 2); \
    W_LGKM("0"); MFMA4(1, 1, 3); \
    MFMA16(1, 0); __builtin_amdgcn_s_setprio(0); \
    asm volatile("s_waitcnt vmcnt(0)" ::: "memory"); \
    __builtin_amdgcn_s_barrier(); \
    __builtin_amdgcn_sched_barrier(0); }

// EPI 0: gelu(v) -> bf16 ; EPI 1: v -> f32 ; EPI 3: v -> bf16
// blockIdx.z==1 (dual mode): use A2/out2/bias1/sum1, W += wz.
template<int EPI>
__global__ __launch_bounds__(512, 2) void gemm256(
        const u16* __restrict__ A, const u16* __restrict__ A2, int lda,
        const u16* __restrict__ W, int wz,
        const float* __restrict__ bias0, const float* __restrict__ bias1,
        void* out, void* out2,
        const double* sum0, const double* sum1,
        int N, int K, int ncut) {
    __shared__ __align__(16) u16 lds[2][2][2][8192];   // [s][d][h], 128 KiB
    if (blockIdx.z) { A = A2; W += wz; out = out2; bias0 = bias1; sum0 = sum1; }

    const int t = threadIdx.x;
    const int l = t & 63;
    const int w = t >> 6;
    const int lr = l & 15, quad = l >> 4;
    const int wm = w >> 2, wn = w & 3;          // 2 x 4 wave grid
    const int NT = K >> 6;

    // T1: bijective XCD swizzle on the flat block id (all grids: nwg%8==0).
    const int nwg  = gridDim.x * gridDim.y;
    const int flat = blockIdx.y * gridDim.x + blockIdx.x;
    const int swz  = (flat & 7) * (nwg >> 3) + (flat >> 3);
    const int bn0 = (swz % gridDim.x) * 256, bm0 = (swz / gridDim.x) * 256;

    // --- staging per-thread constants (pre-swizzled global source) ---
    const int ci0 = t, ci1 = 512 + t;               // 16B chunk ids in half-tile
    const int row0 = ci0 >> 3, row1 = ci1 >> 3;     // row in half (0..127)
    const int cg0 = (ci0 & 7) ^ (row0 & 7);         // global chunk col (swizzle^-1)
    const int cg1 = (ci1 & 7) ^ (row1 & 7);
    const u16* Ab0 = A + (size_t)(bm0 + row0) * lda + cg0 * 8;
    const u16* Ab1 = A + (size_t)(bm0 + row1) * lda + cg1 * 8;
    const u16* Wb0 = W + (size_t)(bn0 + row0) * K + cg0 * 8;
    const u16* Wb1 = W + (size_t)(bn0 + row1) * K + cg1 * 8;
    const size_t ha = (size_t)128 * lda;            // A half-tile row stride
    const size_t hw = (size_t)128 * K;              // B half-tile row stride

    // --- ds_read thread-constant base pointers (swizzle folded in) ---
    const int r0a = wm * 64 + lr;                   // A row-in-half base
    const int cA0u = ((quad) ^ (r0a & 7)) * 8;      // ks=0 chunk, u16 units
    const int r0b = wn * 32 + lr;                   // B row-in-half base
    const int cB0u = ((quad) ^ (r0b & 7)) * 8;
    ldsp lb = (ldsp)&lds[0][0][0][0];
    ldsp vA0 = lb + r0a * 64 + cA0u;                // ks=1 is chunk^4 -> ^32 u16
    ldsp vA1 = lb + r0a * 64 + (cA0u ^ 32);
    ldsp vB0 = lb + 32768 + r0b * 64 + cB0u;        // +65536B = B slab
    ldsp vB1 = lb + 32768 + r0b * 64 + (cB0u ^ 32);

    f32x4 acc[2][2][4][2] = {};                     // [qm][qn][fm][fn]
    bf16x8 af[4][2];                                // [fm][ksub]
    bf16x8 bf[2][2][2];                             // [qn][fn][ksub]

    // --- prologue: stage tile0 into buf0; drain; publish ---
    STG_A(0, 0, 0); STG_B(0, 0, 0); STG_B(0, 1, 0); STG_A(0, 1, 0);
    asm volatile("s_waitcnt vmcnt(0)" ::: "memory");
    __builtin_amdgcn_s_barrier();
    __builtin_amdgcn_sched_barrier(0);

    for (int kt = 0; kt < NT; kt += 2) {            // NT is even (K % 128 == 0)
        GROUP(kt, 0, 1);
        GROUP(kt + 1, 1, 0);
    }

    // --- epilogue ---
    float s0 = sum0 ? (float)(*sum0 * (1.0 / 4194304.0)) : 1.f;
    float s1 = sum1 ? (float)(*sum1 * (1.0 / 4194304.0)) : 1.f;
    #pragma unroll
    for (int qn = 0; qn < 2; ++qn) {
        #pragma unroll
        for (int fn = 0; fn < 2; ++fn) {
            int gcol = bn0 + qn * 128 + wn * 32 + fn * 16 + lr;
            bool lo = gcol < ncut;
            float bv = lo ? bias0[gcol] : bias1[gcol - ncut];
            float sc = lo ? s0 : s1;
            #pragma unroll
            for (int qm = 0; qm < 2; ++qm) {
                #pragma unroll
                for (int fm = 0; fm < 4; ++fm) {
                    #pragma unroll
                    for (int i = 0; i < 4; ++i) {
                        int grow = bm0 + qm * 128 + wm * 64 + fm * 16 + quad * 4 + i;
                        size_t idx = (size_t)grow * N + gcol;
                        float v = acc[qm][qn][fm][fn][i] * sc + bv;
                        if (EPI == 0)      ((u16*)out)[idx]   = f2bf(gelu_fast(v));
                        else if (EPI == 1) ((float*)out)[idx] = v;
                        else               ((u16*)out)[idx]   = f2bf(v);
                    }
                }
            }
        }
    }
}

// ---------- LN1: f = sigmoid(1.2*g)*t ; LN(f) -> bf16 ----------
__global__ void ln1_kernel(const u16* __restrict__ g, const u16* tt,
                           u16* outb,
                           const float* __restrict__ gam, const float* __restrict__ bet) {
    int row = blockIdx.x, t = threadIdx.x;
    int c0 = t * 8;
    uint4 gv = *(const uint4*)(g  + (size_t)row * 2048 + c0);
    uint4 tv = *(const uint4*)(tt + (size_t)row * 2048 + c0);
    u32 gw[4] = {gv.x, gv.y, gv.z, gv.w}, tw[4] = {tv.x, tv.y, tv.z, tv.w};
    float f[8];
    #pragma unroll
    for (int j = 0; j < 4; ++j) {
        f[2 * j]     = sigmoid12(bf2f((u16)(gw[j] & 0xffff))) * bf2f((u16)(tw[j] & 0xffff));
        f[2 * j + 1] = sigmoid12(bf2f((u16)(gw[j] >> 16)))    * bf2f((u16)(tw[j] >> 16));
    }
    float s1 = 0.f, s2 = 0.f;
    #pragma unroll
    for (int j = 0; j < 8; ++j) { s1 += f[j]; s2 += f[j] * f[j]; }
    s1 = wave_reduce_sum(s1); s2 = wave_reduce_sum(s2);
    __shared__ float red[8];
    int lane = t & 63, wv = t >> 6;
    if (lane == 0) { red[wv] = s1; red[4 + wv] = s2; }
    __syncthreads();
    float S1 = red[0] + red[1] + red[2] + red[3];
    float S2 = red[4] + red[5] + red[6] + red[7];
    float mean = S1 * (1.f / 2048.f);
    float var = S2 * (1.f / 2048.f) - mean * mean;
    float r = rsqrtf(var + 1e-5f);
    u16 ob[8];
    #pragma unroll
    for (int j = 0; j < 8; ++j)
        ob[j] = f2bf((f[j] - mean) * r * gam[c0 + j] + bet[c0 + j]);
    *(uint4*)(outb + (size_t)row * 2048 + c0) = *(uint4*)ob;
}

// ---------- LN2: x = fused(bf16) + mlp2(f32, in-place io) ; LN -> f32 io ----------
__global__ void ln2_kernel(const u16* __restrict__ fb, float* io,
                           const float* __restrict__ gam, const float* __restrict__ bet) {
    int row = blockIdx.x, t = threadIdx.x;
    int c0 = t * 8;
    uint4 fv = *(const uint4*)(fb + (size_t)row * 2048 + c0);
    u32 fw[4] = {fv.x, fv.y, fv.z, fv.w};
    float4* iov = (float4*)(io + (size_t)row * 2048 + c0);
    float4 m0 = iov[0], m1 = iov[1];
    float x[8] = {m0.x, m0.y, m0.z, m0.w, m1.x, m1.y, m1.z, m1.w};
    #pragma unroll
    for (int j = 0; j < 4; ++j) {
        x[2 * j]     += bf2f((u16)(fw[j] & 0xffff));
        x[2 * j + 1] += bf2f((u16)(fw[j] >> 16));
    }
    float s1 = 0.f, s2 = 0.f;
    #pragma unroll
    for (int j = 0; j < 8; ++j) { s1 += x[j]; s2 += x[j] * x[j]; }
    s1 = wave_reduce_sum(s1); s2 = wave_reduce_sum(s2);
    __shared__ float red[8];
    int lane = t & 63, wv = t >> 6;
    if (lane == 0) { red[wv] = s1; red[4 + wv] = s2; }
    __syncthreads();
    float S1 = red[0] + red[1] + red[2] + red[3];
    float S2 = red[4] + red[5] + red[6] + red[7];
    float mean = S1 * (1.f / 2048.f);
    float var = S2 * (1.f / 2048.f) - mean * mean;
    float r = rsqrtf(var + 1e-5f);
    float o[8];
    #pragma unroll
    for (int j = 0; j < 8; ++j)
        o[j] = (x[j] - mean) * r * gam[c0 + j] + bet[c0 + j];
    iov[0] = make_float4(o[0], o[1], o[2], o[3]);
    iov[1] = make_float4(o[4], o[5], o[6], o[7]);
}

// ---------- launch ----------
extern "C" void kernel_launch(void* const* d_in, const int* in_sizes, int n_in,
                              void* d_out, int out_size, void* d_ws, size_t ws_size,
                              hipStream_t stream) {
    const float* zb  = (const float*)d_in[0];
    const float* za  = (const float*)d_in[1];
    const float* ze  = (const float*)d_in[2];
    const float* zm  = (const float*)d_in[3];
    const float* zs  = (const float*)d_in[4];
    const float* gw1 = (const float*)d_in[5];  const float* gb1 = (const float*)d_in[6];
    const float* gw2 = (const float*)d_in[7];  const float* gb2 = (const float*)d_in[8];
    const float* tw1 = (const float*)d_in[9];  const float* tb1 = (const float*)d_in[10];
    const float* tw2 = (const float*)d_in[11]; const float* tb2 = (const float*)d_in[12];
    const float* mw1 = (const float*)d_in[13]; const float* mb1 = (const float*)d_in[14];
    const float* mw2 = (const float*)d_in[15]; const float* mb2 = (const float*)d_in[16];
    const float* l1g = (const float*)d_in[17]; const float* l1b = (const float*)d_in[18];
    const float* l2g = (const float*)d_in[19]; const float* l2b = (const float*)d_in[20];

    char* wsb = (char*)d_ws;
    // lifetime-aliased layout (MiB offsets):
    //   [0,32)    combined (dead after G12) -> gbuf (G34 z=0 out, dead after LN1)
    //   [32,64)   wq[0..3] (wq[0,1] dead after G12, wq[2,3] dead after G34)
    //   [64,96)   tbuf (G34 z=1 out) -> fusedb (LN1 in-place alias, live to LN2)
    //   [96,128)  mwq (mlp weights bf16, live to G6)
    //   [128,192) partials (1KiB, dead after absmean2) -> HgHt (dead after G34) -> M1
    //   [192]     sums (32 B)
    // AUDIT: tbuf must NOT overlap wq[2,3] [48,64) (race fixed in prior session).
    u16*   combined = (u16*)(wsb + 0);
    u16*   gbuf     = (u16*)(wsb + 0);
    u16*   wq       = (u16*)(wsb + 33554432);
    u16*   tbuf     = (u16*)(wsb + 67108864);
    u16*   fusedb   = (u16*)(wsb + 67108864);
    u16*   mwq      = (u16*)(wsb + 100663296);
    u16*   HgHt     = (u16*)(wsb + 134217728);
    u16*   M1       = (u16*)(wsb + 134217728);
    float* partials = (float*)(wsb + 134217728);
    double* sums    = (double*)(wsb + 201326592);
    float* mlp2     = (float*)d_out;              // G6 out, LN2 in-place

    // deterministic absmean (no atomics -> bit-identical across replays)
    absmean1_kernel<<<dim3(64, 4), 256, 0, stream>>>(gw1, tw1, gw2, tw2, partials);
    absmean2_kernel<<<4, 64, 0, stream>>>(partials, sums);
    prep_kernel<<<dim3(4096, 6), 256, 0, stream>>>(gw1, tw1, gw2, tw2, mw1, mw2, wq, mwq, sums);
    concat_kernel<<<B_ROWS, 256, 0, stream>>>(zb, za, ze, zm, zs, combined);

    // G12: HgHt = gelu(scale*(combined @ [gw1q;tw1q]^T) + [gb1;tb1]), N=4096
    gemm256<0><<<dim3(16, 32, 1), 512, 0, stream>>>(
        combined, nullptr, 2048, wq, 0, gb1, tb1, HgHt, nullptr,
        &sums[0], &sums[1], 4096, 2048, 2048);
    // G34 (dual-z): g = s2*(Hg @ gw2q^T)+gb2 ; t = s3*(Ht @ tw2q^T)+tb2  (bf16)
    gemm256<3><<<dim3(8, 32, 2), 512, 0, stream>>>(
        HgHt, HgHt + 2048, 4096, wq + 8388608, 4194304, gb2, tb2, gbuf, tbuf,
        &sums[2], &sums[3], 2048, 2048, 2048);
    // LN1: fusedb = LN(sigmoid(1.2*g)*t)  (in-place over tbuf, same-thread RMW)
    ln1_kernel<<<B_ROWS, 256, 0, stream>>>(gbuf, tbuf, fusedb, l1g, l1b);
    // G5: M1 = gelu(fusedb @ mlp_w1^T + mb1), N=4096
    gemm256<0><<<dim3(16, 32, 1), 512, 0, stream>>>(
        fusedb, nullptr, 2048, mwq, 0, mb1, mb1, M1, nullptr,
        nullptr, nullptr, 4096, 2048, 4096);
    // G6: mlp2 = M1 @ mlp_w2^T + mb2 (f32, K=4096) -> d_out
    gemm256<1><<<dim3(8, 32, 1), 512, 0, stream>>>(
        M1, nullptr, 4096, mwq + 8388608, 0, mb2, mb2, mlp2, nullptr,
        nullptr, nullptr, 2048, 4096, 2048);
    // LN2: d_out = LN(fusedb + mlp2), f32 in-place
    ln2_kernel<<<B_ROWS, 256, 0, stream>>>(fusedb, mlp2, l2g, l2b);
}

// Round 6
// 817.411 us; speedup vs baseline: 1.0118x; 1.0118x over previous
//
#include <hip/hip_runtime.h>

typedef unsigned short u16;
typedef unsigned int u32;
typedef __bf16 bf16x8 __attribute__((ext_vector_type(8)));
typedef float f32x4 __attribute__((ext_vector_type(4)));
typedef const __attribute__((address_space(3))) u16* ldsp;

#define B_ROWS 8192

// ---------- helpers ----------
__device__ __forceinline__ float bf2f(u16 h) {
    union { u32 u; float f; } v; v.u = ((u32)h) << 16; return v.f;
}
__device__ __forceinline__ u16 f2bf(float f) {
    union { float f; u32 u; } v; v.f = f;
    u32 r = v.u + 0x7fffu + ((v.u >> 16) & 1u);   // RNE
    return (u16)(r >> 16);
}
// tanh-approx gelu, overflow-safe (e=inf -> th=1)
__device__ __forceinline__ float gelu_fast(float x) {
    float u = x * (0.7978845608f + 0.0356774081f * x * x);
    float e = __expf(2.f * u);
    float th = 1.f - 2.f / (e + 1.f);
    return 0.5f * x * (1.f + th);
}
__device__ __forceinline__ float sigmoid12(float g) {
    return 1.f / (1.f + __expf(-1.2f * g));
}
__device__ __forceinline__ float wave_reduce_sum(float v) {
    #pragma unroll
    for (int m = 32; m; m >>= 1) v += __shfl_xor(v, m, 64);
    return v;
}
__device__ __forceinline__ void async16(const void* g, void* l) {
    __builtin_amdgcn_global_load_lds((const __attribute__((address_space(1))) u32*)g,
                                     (__attribute__((address_space(3))) u32*)l, 16, 0, 0);
}
// inline-asm LDS read: keeps the compiler from seeing an LDS access that
// aliases the global_load_lds writes (it would insert s_waitcnt vmcnt(0)
// and destroy the counted-vmcnt pipeline).
template<int OFF>
__device__ __forceinline__ bf16x8 dsr(ldsp a) {
    bf16x8 r;
    asm volatile("ds_read_b128 %0, %1 offset:%c2"
                 : "=v"(r) : "v"(a), "i"(OFF) : "memory");
    return r;
}

// ---------- absmean stage 1: deterministic block partials (no atomics) ----------
__global__ void absmean1_kernel(const float* __restrict__ w0, const float* __restrict__ w1,
                                const float* __restrict__ w2, const float* __restrict__ w3,
                                float* __restrict__ partials) {
    const float* w = (blockIdx.y == 0) ? w0 : (blockIdx.y == 1) ? w1 : (blockIdx.y == 2) ? w2 : w3;
    int base = blockIdx.x * 16384;   // vec4 units
    float acc = 0.f;
    for (int j = threadIdx.x; j < 16384; j += 256) {
        float4 v = ((const float4*)w)[base + j];
        acc += fabsf(v.x) + fabsf(v.y) + fabsf(v.z) + fabsf(v.w);
    }
    acc = wave_reduce_sum(acc);
    __shared__ float red[4];
    int lane = threadIdx.x & 63, wv = threadIdx.x >> 6;
    if (lane == 0) red[wv] = acc;
    __syncthreads();
    if (threadIdx.x == 0)
        partials[blockIdx.y * 64 + blockIdx.x] = red[0] + red[1] + red[2] + red[3];
}

// ---------- absmean stage 2: fixed-order combine ----------
__global__ void absmean2_kernel(const float* __restrict__ partials, double* __restrict__ sums) {
    float v = partials[blockIdx.x * 64 + threadIdx.x];
    v = wave_reduce_sum(v);
    if (threadIdx.x == 0) sums[blockIdx.x] = (double)v;
}

// ---------- prep: y<4 ternary-quantize {-1,0,1} bf16; y=4,5 cvt mlp weights ----------
__global__ void prep_kernel(const float* __restrict__ w0, const float* __restrict__ w1,
                            const float* __restrict__ w2, const float* __restrict__ w3,
                            const float* __restrict__ mw1, const float* __restrict__ mw2,
                            u16* __restrict__ wq, u16* __restrict__ mwq,
                            const double* __restrict__ sums) {
    int y = blockIdx.y;
    int i = blockIdx.x * 256 + threadIdx.x;   // vec4 index, grid.x = 4096
    if (y < 4) {
        const float* w = (y == 0) ? w0 : (y == 1) ? w1 : (y == 2) ? w2 : w3;
        float s = (float)(sums[y] * (1.0 / 4194304.0));
        float den = s + 1e-5f;
        float4 v = ((const float4*)w)[i];
        ushort4 o;
        o.x = f2bf(rintf(fminf(fmaxf(v.x / den, -1.f), 1.f)));
        o.y = f2bf(rintf(fminf(fmaxf(v.y / den, -1.f), 1.f)));
        o.z = f2bf(rintf(fminf(fmaxf(v.z / den, -1.f), 1.f)));
        o.w = f2bf(rintf(fminf(fmaxf(v.w / den, -1.f), 1.f)));
        ((ushort4*)(wq + (size_t)y * 4194304))[i] = o;
    } else {
        const float* src = (y == 4) ? mw1 : mw2;
        u16* dst = mwq + (y == 4 ? 0 : 8388608);
        #pragma unroll
        for (int r = 0; r < 2; ++r) {
            int j = i + r * 1048576;
            float4 v = ((const float4*)src)[j];
            ushort4 o = {f2bf(v.x), f2bf(v.y), f2bf(v.z), f2bf(v.w)};
            ((ushort4*)dst)[j] = o;
        }
    }
}

// ---------- concat 5 fp32 inputs -> combined [8192,2048] bf16 ----------
__global__ void concat_kernel(const float* __restrict__ zb, const float* __restrict__ za,
                              const float* __restrict__ ze, const float* __restrict__ zm,
                              const float* __restrict__ zs, u16* __restrict__ out) {
    int row = blockIdx.x, t = threadIdx.x;
    int col = t * 8;
    const float* src; int scol, stride;
    if (col < 512)       { src = zb; scol = col;        stride = 512; }
    else if (col < 768)  { src = za; scol = col - 512;  stride = 256; }
    else if (col < 1024) { src = ze; scol = col - 768;  stride = 256; }
    else if (col < 1536) { src = zm; scol = col - 1024; stride = 512; }
    else                 { src = zs; scol = col - 1536; stride = 512; }
    const float4* s4 = (const float4*)(src + (size_t)row * stride + scol);
    float4 a = s4[0], b = s4[1];
    ushort4 p0 = {f2bf(a.x), f2bf(a.y), f2bf(a.z), f2bf(a.w)};
    ushort4 p1 = {f2bf(b.x), f2bf(b.y), f2bf(b.z), f2bf(b.w)};
    u16* o = out + (size_t)row * 2048 + col;
    *(ushort4*)o = p0;
    *(ushort4*)(o + 4) = p1;
}

// ========= 256x256 GEMM, 1-ahead operand pipeline, ping-pong regs (v5) =========
// C = scale * (A[M,K(lda)] * W[N,K]^T) + bias
// 512 threads = 8 waves (2M x 4N); per-wave output 128x64; BK=64; LDS 128KiB.
// LDS layout: lds[A=0/B=1][dbuf][half(128 rows)][128x64 bf16], rows are 128B.
// T2 swizzle: 16B chunk c stored at c ^ (row&7), pre-swizzled global source +
//   linear global_load_lds dest, same XOR on read bases.
//
// v5: reads are issued ONE MFMA-BURST AHEAD of consumption so the burst hides
// LDS latency+queue (v4 issued then immediately waited: ~400cyc exposed/group).
// Register trick (stays under the 256-reg cap: acc 128 AGPR + ~125 VGPR):
// A-half0 (af_[0..3]) dies progressively inside Q01, so A-half1 fragments are
// read INTO THE SAME BUFFER as its halves die:
//   entry: read bf0(4) af0(8); stage t+1 -> e (8 gloads, vmcnt); lgkm(0) [bubble]
//   issue bf1(4) | Q00 = 16 MFMA (af0 x bf0)
//   lgkm(0)      | Q01-fm01 (af0[01] x bf1)   -- af0[01] last use
//   issue af1[01] -> af_[01] | Q01-fm23 (af0[23] x bf1)  -- af0[23] last use
//   lgkm(0); issue af1[23] -> af_[23] | Q11-fm01 (af_[01] x bf1)
//   lgkm(0)      | Q11-fm23, Q10 = 24 MFMA (af_ x bf1/bf0)
//   vmcnt(0); s_barrier   (publish buf e; staging had ~full-tile cover)
// Hazards: staging targets buf e (no reader this tile; e's readers closed at
// prev barrier). bf0 live to Q10, never overwritten intra-tile. Accumulation
// order per output element unchanged -> bit-identical numerics vs r5.
#define STG_A(d, h, kt_) { \
    async16(Ab0 + (size_t)(h) * ha + (size_t)(kt_) * 64, &lds[0][d][h][ci0 * 8]); \
    async16(Ab1 + (size_t)(h) * ha + (size_t)(kt_) * 64, &lds[0][d][h][ci1 * 8]); }
#define STG_B(d, h, kt_) { \
    async16(Wb0 + (size_t)(h) * hw + (size_t)(kt_) * 64, &lds[1][d][h][ci0 * 8]); \
    async16(Wb1 + (size_t)(h) * hw + (size_t)(kt_) * 64, &lds[1][d][h][ci1 * 8]); }
#define AOFF(d, h, fm) (((d) * 2 + (h)) * 16384 + (fm) * 2048)
#define BOFF(d, h, fn) (((d) * 2 + (h)) * 16384 + (fn) * 2048)
#define LDA_H(d, h, fm) { \
    af_[fm][0] = dsr<AOFF(d,h,fm)>(vA0); af_[fm][1] = dsr<AOFF(d,h,fm)>(vA1); }
#define LDB_P(BUF, d, h) { \
    BUF[0][0] = dsr<BOFF(d,h,0)>(vB0); BUF[0][1] = dsr<BOFF(d,h,0)>(vB1); \
    BUF[1][0] = dsr<BOFF(d,h,1)>(vB0); BUF[1][1] = dsr<BOFF(d,h,1)>(vB1); }
#define W_LGKM0 { \
    asm volatile("s_waitcnt lgkmcnt(0)" ::: "memory"); \
    __builtin_amdgcn_sched_barrier(0); }
#define SP1 __builtin_amdgcn_s_setprio(1);
#define SP0 __builtin_amdgcn_s_setprio(0);
#define MFMA1P(qm, qn, fm, fn, ks, BUF) \
    acc[qm][qn][fm][fn] = __builtin_amdgcn_mfma_f32_16x16x32_bf16(af_[fm][ks], BUF[fn][ks], acc[qm][qn][fm][fn], 0, 0, 0);
#define MFMA_Q8(qm, qn, fmb, BUF) { \
    MFMA1P(qm, qn, (fmb)+0, 0, 0, BUF); MFMA1P(qm, qn, (fmb)+0, 0, 1, BUF); \
    MFMA1P(qm, qn, (fmb)+0, 1, 0, BUF); MFMA1P(qm, qn, (fmb)+0, 1, 1, BUF); \
    MFMA1P(qm, qn, (fmb)+1, 0, 0, BUF); MFMA1P(qm, qn, (fmb)+1, 0, 1, BUF); \
    MFMA1P(qm, qn, (fmb)+1, 1, 0, BUF); MFMA1P(qm, qn, (fmb)+1, 1, 1, BUF); }
#define GROUP_P(ktv, d, e) { \
    LDB_P(bf0_, d, 0); \
    LDA_H(d, 0, 0); LDA_H(d, 0, 1); LDA_H(d, 0, 2); LDA_H(d, 0, 3); \
    if ((ktv) + 1 < NT) { \
        STG_A(e, 0, (ktv) + 1); STG_B(e, 0, (ktv) + 1); \
        STG_B(e, 1, (ktv) + 1); STG_A(e, 1, (ktv) + 1); } \
    W_LGKM0; \
    LDB_P(bf1_, d, 1); \
    SP1; MFMA_Q8(0, 0, 0, bf0_); MFMA_Q8(0, 0, 2, bf0_); SP0; \
    W_LGKM0; \
    SP1; MFMA_Q8(0, 1, 0, bf1_); SP0; \
    LDA_H(d, 1, 0); LDA_H(d, 1, 1); \
    SP1; MFMA_Q8(0, 1, 2, bf1_); SP0; \
    W_LGKM0; \
    LDA_H(d, 1, 2); LDA_H(d, 1, 3); \
    SP1; MFMA_Q8(1, 1, 0, bf1_); SP0; \
    W_LGKM0; \
    SP1; MFMA_Q8(1, 1, 2, bf1_); MFMA_Q8(1, 0, 0, bf0_); MFMA_Q8(1, 0, 2, bf0_); SP0; \
    asm volatile("s_waitcnt vmcnt(0)" ::: "memory"); \
    __builtin_amdgcn_s_barrier(); \
    __builtin_amdgcn_sched_barrier(0); }

// EPI 0: gelu(v) -> bf16 ; EPI 1: v -> f32 ; EPI 3: v -> bf16
// blockIdx.z==1 (dual mode): use A2/out2/bias1/sum1, W += wz.
template<int EPI>
__global__ __launch_bounds__(512, 2) void gemm256(
        const u16* __restrict__ A, const u16* __restrict__ A2, int lda,
        const u16* __restrict__ W, int wz,
        const float* __restrict__ bias0, const float* __restrict__ bias1,
        void* out, void* out2,
        const double* sum0, const double* sum1,
        int N, int K, int ncut) {
    __shared__ __align__(16) u16 lds[2][2][2][8192];   // [s][d][h], 128 KiB
    if (blockIdx.z) { A = A2; W += wz; out = out2; bias0 = bias1; sum0 = sum1; }

    const int t = threadIdx.x;
    const int l = t & 63;
    const int w = t >> 6;
    const int lr = l & 15, quad = l >> 4;
    const int wm = w >> 2, wn = w & 3;          // 2 x 4 wave grid
    const int NT = K >> 6;

    // T1: bijective XCD swizzle on the flat block id (all grids: nwg%8==0).
    const int nwg  = gridDim.x * gridDim.y;
    const int flat = blockIdx.y * gridDim.x + blockIdx.x;
    const int swz  = (flat & 7) * (nwg >> 3) + (flat >> 3);
    const int bn0 = (swz % gridDim.x) * 256, bm0 = (swz / gridDim.x) * 256;

    // --- staging per-thread constants (pre-swizzled global source) ---
    const int ci0 = t, ci1 = 512 + t;               // 16B chunk ids in half-tile
    const int row0 = ci0 >> 3, row1 = ci1 >> 3;     // row in half (0..127)
    const int cg0 = (ci0 & 7) ^ (row0 & 7);         // global chunk col (swizzle^-1)
    const int cg1 = (ci1 & 7) ^ (row1 & 7);
    const u16* Ab0 = A + (size_t)(bm0 + row0) * lda + cg0 * 8;
    const u16* Ab1 = A + (size_t)(bm0 + row1) * lda + cg1 * 8;
    const u16* Wb0 = W + (size_t)(bn0 + row0) * K + cg0 * 8;
    const u16* Wb1 = W + (size_t)(bn0 + row1) * K + cg1 * 8;
    const size_t ha = (size_t)128 * lda;            // A half-tile row stride
    const size_t hw = (size_t)128 * K;              // B half-tile row stride

    // --- ds_read thread-constant base pointers (swizzle folded in) ---
    const int r0a = wm * 64 + lr;                   // A row-in-half base
    const int cA0u = ((quad) ^ (r0a & 7)) * 8;      // ks=0 chunk, u16 units
    const int r0b = wn * 32 + lr;                   // B row-in-half base
    const int cB0u = ((quad) ^ (r0b & 7)) * 8;
    ldsp lb = (ldsp)&lds[0][0][0][0];
    ldsp vA0 = lb + r0a * 64 + cA0u;                // ks=1 is chunk^4 -> ^32 u16
    ldsp vA1 = lb + r0a * 64 + (cA0u ^ 32);
    ldsp vB0 = lb + 32768 + r0b * 64 + cB0u;        // +65536B = B slab
    ldsp vB1 = lb + 32768 + r0b * 64 + (cB0u ^ 32);

    f32x4 acc[2][2][4][2] = {};                     // [qm][qn][fm][fn]
    bf16x8 af_[4][2];                               // ping-pong A buffer
    bf16x8 bf0_[2][2], bf1_[2][2];                  // B halves

    // --- prologue: stage tile0 into buf0; drain; publish ---
    STG_A(0, 0, 0); STG_B(0, 0, 0); STG_B(0, 1, 0); STG_A(0, 1, 0);
    asm volatile("s_waitcnt vmcnt(0)" ::: "memory");
    __builtin_amdgcn_s_barrier();
    __builtin_amdgcn_sched_barrier(0);

    for (int kt = 0; kt < NT; kt += 2) {            // NT is even (K % 128 == 0)
        GROUP_P(kt, 0, 1);
        GROUP_P(kt + 1, 1, 0);
    }

    // --- epilogue ---
    float s0 = sum0 ? (float)(*sum0 * (1.0 / 4194304.0)) : 1.f;
    float s1 = sum1 ? (float)(*sum1 * (1.0 / 4194304.0)) : 1.f;
    #pragma unroll
    for (int qn = 0; qn < 2; ++qn) {
        #pragma unroll
        for (int fn = 0; fn < 2; ++fn) {
            int gcol = bn0 + qn * 128 + wn * 32 + fn * 16 + lr;
            bool lo = gcol < ncut;
            float bv = lo ? bias0[gcol] : bias1[gcol - ncut];
            float sc = lo ? s0 : s1;
            #pragma unroll
            for (int qm = 0; qm < 2; ++qm) {
                #pragma unroll
                for (int fm = 0; fm < 4; ++fm) {
                    #pragma unroll
                    for (int i = 0; i < 4; ++i) {
                        int grow = bm0 + qm * 128 + wm * 64 + fm * 16 + quad * 4 + i;
                        size_t idx = (size_t)grow * N + gcol;
                        float v = acc[qm][qn][fm][fn][i] * sc + bv;
                        if (EPI == 0)      ((u16*)out)[idx]   = f2bf(gelu_fast(v));
                        else if (EPI == 1) ((float*)out)[idx] = v;
                        else               ((u16*)out)[idx]   = f2bf(v);
                    }
                }
            }
        }
    }
}

// ---------- LN1: f = sigmoid(1.2*g)*t ; LN(f) -> bf16 ----------
__global__ void ln1_kernel(const u16* __restrict__ g, const u16* tt,
                           u16* outb,
                           const float* __restrict__ gam, const float* __restrict__ bet) {
    int row = blockIdx.x, t = threadIdx.x;
    int c0 = t * 8;
    uint4 gv = *(const uint4*)(g  + (size_t)row * 2048 + c0);
    uint4 tv = *(const uint4*)(tt + (size_t)row * 2048 + c0);
    u32 gw[4] = {gv.x, gv.y, gv.z, gv.w}, tw[4] = {tv.x, tv.y, tv.z, tv.w};
    float f[8];
    #pragma unroll
    for (int j = 0; j < 4; ++j) {
        f[2 * j]     = sigmoid12(bf2f((u16)(gw[j] & 0xffff))) * bf2f((u16)(tw[j] & 0xffff));
        f[2 * j + 1] = sigmoid12(bf2f((u16)(gw[j] >> 16)))    * bf2f((u16)(tw[j] >> 16));
    }
    float s1 = 0.f, s2 = 0.f;
    #pragma unroll
    for (int j = 0; j < 8; ++j) { s1 += f[j]; s2 += f[j] * f[j]; }
    s1 = wave_reduce_sum(s1); s2 = wave_reduce_sum(s2);
    __shared__ float red[8];
    int lane = t & 63, wv = t >> 6;
    if (lane == 0) { red[wv] = s1; red[4 + wv] = s2; }
    __syncthreads();
    float S1 = red[0] + red[1] + red[2] + red[3];
    float S2 = red[4] + red[5] + red[6] + red[7];
    float mean = S1 * (1.f / 2048.f);
    float var = S2 * (1.f / 2048.f) - mean * mean;
    float r = rsqrtf(var + 1e-5f);
    u16 ob[8];
    #pragma unroll
    for (int j = 0; j < 8; ++j)
        ob[j] = f2bf((f[j] - mean) * r * gam[c0 + j] + bet[c0 + j]);
    *(uint4*)(outb + (size_t)row * 2048 + c0) = *(uint4*)ob;
}

// ---------- LN2: x = fused(bf16) + mlp2(f32, in-place io) ; LN -> f32 io ----------
__global__ void ln2_kernel(const u16* __restrict__ fb, float* io,
                           const float* __restrict__ gam, const float* __restrict__ bet) {
    int row = blockIdx.x, t = threadIdx.x;
    int c0 = t * 8;
    uint4 fv = *(const uint4*)(fb + (size_t)row * 2048 + c0);
    u32 fw[4] = {fv.x, fv.y, fv.z, fv.w};
    float4* iov = (float4*)(io + (size_t)row * 2048 + c0);
    float4 m0 = iov[0], m1 = iov[1];
    float x[8] = {m0.x, m0.y, m0.z, m0.w, m1.x, m1.y, m1.z, m1.w};
    #pragma unroll
    for (int j = 0; j < 4; ++j) {
        x[2 * j]     += bf2f((u16)(fw[j] & 0xffff));
        x[2 * j + 1] += bf2f((u16)(fw[j] >> 16));
    }
    float s1 = 0.f, s2 = 0.f;
    #pragma unroll
    for (int j = 0; j < 8; ++j) { s1 += x[j]; s2 += x[j] * x[j]; }
    s1 = wave_reduce_sum(s1); s2 = wave_reduce_sum(s2);
    __shared__ float red[8];
    int lane = t & 63, wv = t >> 6;
    if (lane == 0) { red[wv] = s1; red[4 + wv] = s2; }
    __syncthreads();
    float S1 = red[0] + red[1] + red[2] + red[3];
    float S2 = red[4] + red[5] + red[6] + red[7];
    float mean = S1 * (1.f / 2048.f);
    float var = S2 * (1.f / 2048.f) - mean * mean;
    float r = rsqrtf(var + 1e-5f);
    float o[8];
    #pragma unroll
    for (int j = 0; j < 8; ++j)
        o[j] = (x[j] - mean) * r * gam[c0 + j] + bet[c0 + j];
    iov[0] = make_float4(o[0], o[1], o[2], o[3]);
    iov[1] = make_float4(o[4], o[5], o[6], o[7]);
}

// ---------- launch ----------
extern "C" void kernel_launch(void* const* d_in, const int* in_sizes, int n_in,
                              void* d_out, int out_size, void* d_ws, size_t ws_size,
                              hipStream_t stream) {
    const float* zb  = (const float*)d_in[0];
    const float* za  = (const float*)d_in[1];
    const float* ze  = (const float*)d_in[2];
    const float* zm  = (const float*)d_in[3];
    const float* zs  = (const float*)d_in[4];
    const float* gw1 = (const float*)d_in[5];  const float* gb1 = (const float*)d_in[6];
    const float* gw2 = (const float*)d_in[7];  const float* gb2 = (const float*)d_in[8];
    const float* tw1 = (const float*)d_in[9];  const float* tb1 = (const float*)d_in[10];
    const float* tw2 = (const float*)d_in[11]; const float* tb2 = (const float*)d_in[12];
    const float* mw1 = (const float*)d_in[13]; const float* mb1 = (const float*)d_in[14];
    const float* mw2 = (const float*)d_in[15]; const float* mb2 = (const float*)d_in[16];
    const float* l1g = (const float*)d_in[17]; const float* l1b = (const float*)d_in[18];
    const float* l2g = (const float*)d_in[19]; const float* l2b = (const float*)d_in[20];

    char* wsb = (char*)d_ws;
    // lifetime-aliased layout (MiB offsets):
    //   [0,32)    combined (dead after G12) -> gbuf (G34 z=0 out, dead after LN1)
    //   [32,64)   wq[0..3] (wq[0,1] dead after G12, wq[2,3] dead after G34)
    //   [64,96)   tbuf (G34 z=1 out) -> fusedb (LN1 in-place alias, live to LN2)
    //   [96,128)  mwq (mlp weights bf16, live to G6)
    //   [128,192) partials (1KiB, dead after absmean2) -> HgHt (dead after G34) -> M1
    //   [192]     sums (32 B)
    // AUDIT: tbuf must NOT overlap wq[2,3] [48,64) (race fixed in prior session).
    u16*   combined = (u16*)(wsb + 0);
    u16*   gbuf     = (u16*)(wsb + 0);
    u16*   wq       = (u16*)(wsb + 33554432);
    u16*   tbuf     = (u16*)(wsb + 67108864);
    u16*   fusedb   = (u16*)(wsb + 67108864);
    u16*   mwq      = (u16*)(wsb + 100663296);
    u16*   HgHt     = (u16*)(wsb + 134217728);
    u16*   M1       = (u16*)(wsb + 134217728);
    float* partials = (float*)(wsb + 134217728);
    double* sums    = (double*)(wsb + 201326592);
    float* mlp2     = (float*)d_out;              // G6 out, LN2 in-place

    // deterministic absmean (no atomics -> bit-identical across replays)
    absmean1_kernel<<<dim3(64, 4), 256, 0, stream>>>(gw1, tw1, gw2, tw2, partials);
    absmean2_kernel<<<4, 64, 0, stream>>>(partials, sums);
    prep_kernel<<<dim3(4096, 6), 256, 0, stream>>>(gw1, tw1, gw2, tw2, mw1, mw2, wq, mwq, sums);
    concat_kernel<<<B_ROWS, 256, 0, stream>>>(zb, za, ze, zm, zs, combined);

    // G12: HgHt = gelu(scale*(combined @ [gw1q;tw1q]^T) + [gb1;tb1]), N=4096
    gemm256<0><<<dim3(16, 32, 1), 512, 0, stream>>>(
        combined, nullptr, 2048, wq, 0, gb1, tb1, HgHt, nullptr,
        &sums[0], &sums[1], 4096, 2048, 2048);
    // G34 (dual-z): g = s2*(Hg @ gw2q^T)+gb2 ; t = s3*(Ht @ tw2q^T)+tb2  (bf16)
    gemm256<3><<<dim3(8, 32, 2), 512, 0, stream>>>(
        HgHt, HgHt + 2048, 4096, wq + 8388608, 4194304, gb2, tb2, gbuf, tbuf,
        &sums[2], &sums[3], 2048, 2048, 2048);
    // LN1: fusedb = LN(sigmoid(1.2*g)*t)  (in-place over tbuf, same-thread RMW)
    ln1_kernel<<<B_ROWS, 256, 0, stream>>>(gbuf, tbuf, fusedb, l1g, l1b);
    // G5: M1 = gelu(fusedb @ mlp_w1^T + mb1), N=4096
    gemm256<0><<<dim3(16, 32, 1), 512, 0, stream>>>(
        fusedb, nullptr, 2048, mwq, 0, mb1, mb1, M1, nullptr,
        nullptr, nullptr, 4096, 2048, 4096);
    // G6: mlp2 = M1 @ mlp_w2^T + mb2 (f32, K=4096) -> d_out
    gemm256<1><<<dim3(8, 32, 1), 512, 0, stream>>>(
        M1, nullptr, 4096, mwq + 8388608, 0, mb2, mb2, mlp2, nullptr,
        nullptr, nullptr, 2048, 4096, 2048);
    // LN2: d_out = LN(fusedb + mlp2), f32 in-place
    ln2_kernel<<<B_ROWS, 256, 0, stream>>>(fusedb, mlp2, l2g, l2b);
}